// Round 1
// baseline (196.015 us; speedup 1.0000x reference)
//
#include <hip/hip_runtime.h>

#define NB 64      // L*B batches
#define T 1024     // t1 == t2
#define HD 128     // h
#define LDA 136    // padded LDS row stride in shorts (+8 -> conflict-minimal b128)
#define INF_BITS 0x7F800000u

typedef __attribute__((ext_vector_type(8))) short bf16x8;
typedef __attribute__((ext_vector_type(4))) float f32x4;

// fp32 -> bf16 bits, round-to-nearest-even (manual, no header/type risk)
static __device__ __forceinline__ short f2bf(float f) {
    unsigned u = __float_as_uint(f);
    u += 0x7FFFu + ((u >> 16) & 1u);
    return (short)(u >> 16);
}

// Phase 0: init col-min workspace to +inf, zero the two sum accumulators.
__global__ void wmd_init(unsigned* __restrict__ g_colmin, float* __restrict__ sums) {
    int t = blockIdx.x * 256 + threadIdx.x;
    if (t < NB * T) g_colmin[t] = INF_BITS;
    if (t < 2) sums[t] = 0.f;
}

// Phase 1: fused bf16-MFMA GEMM + min tracking.
// Grid: (8 i-tiles, 64 batches). Block: 256 threads = 2x2 waves of 64x64.
__global__ __launch_bounds__(256, 2)
void wmd_main(const float* __restrict__ x, const float* __restrict__ y,
              unsigned* __restrict__ g_colmin, unsigned* __restrict__ g_rowmin) {
    __shared__ short a_sm[128 * LDA];
    __shared__ short b_sm[128 * LDA];
    __shared__ float x2_sm[128];
    __shared__ float y2_sm[128];
    __shared__ unsigned row_min_sm[128];
    __shared__ unsigned col_min_sm[128];

    const int tid  = threadIdx.x;
    const int n    = blockIdx.y;
    const int i0   = blockIdx.x * 128;
    const int lane = tid & 63;
    const int wave = tid >> 6;
    const int wm   = wave >> 1, wn = wave & 1;
    const int l16  = lane & 15, quad = lane >> 4;
    const float FINF = __uint_as_float(INF_BITS);

    // ---- stage A tile (fp32 -> bf16) + exact fp32 row norms ----
    {
        const float4* xg = reinterpret_cast<const float4*>(x + (size_t)(n * T + i0) * HD);
        #pragma unroll
        for (int it = 0; it < 16; ++it) {
            int idx = it * 256 + tid;
            int row = idx >> 5, c4 = idx & 31;       // 32 float4 per row of 128
            float4 v = xg[idx];
            short4 s4;
            s4.x = f2bf(v.x); s4.y = f2bf(v.y); s4.z = f2bf(v.z); s4.w = f2bf(v.w);
            *reinterpret_cast<short4*>(&a_sm[row * LDA + c4 * 4]) = s4;
            float p = v.x * v.x + v.y * v.y + v.z * v.z + v.w * v.w;
            p += __shfl_xor(p, 1);  p += __shfl_xor(p, 2);  p += __shfl_xor(p, 4);
            p += __shfl_xor(p, 8);  p += __shfl_xor(p, 16);
            if ((tid & 31) == 0) x2_sm[row] = p;     // half-wave owns one full row
        }
    }
    if (tid < 128) { row_min_sm[tid] = INF_BITS; col_min_sm[tid] = INF_BITS; }
    __syncthreads();

    for (int jt = 0; jt < 8; ++jt) {
        // ---- stage B tile + row norms ----
        {
            const float4* yg = reinterpret_cast<const float4*>(y + (size_t)(n * T + jt * 128) * HD);
            #pragma unroll
            for (int it = 0; it < 16; ++it) {
                int idx = it * 256 + tid;
                int row = idx >> 5, c4 = idx & 31;
                float4 v = yg[idx];
                short4 s4;
                s4.x = f2bf(v.x); s4.y = f2bf(v.y); s4.z = f2bf(v.z); s4.w = f2bf(v.w);
                *reinterpret_cast<short4*>(&b_sm[row * LDA + c4 * 4]) = s4;
                float p = v.x * v.x + v.y * v.y + v.z * v.z + v.w * v.w;
                p += __shfl_xor(p, 1);  p += __shfl_xor(p, 2);  p += __shfl_xor(p, 4);
                p += __shfl_xor(p, 8);  p += __shfl_xor(p, 16);
                if ((tid & 31) == 0) y2_sm[row] = p;
            }
        }
        __syncthreads();

        // ---- MFMA: 64x64 per wave, 4 K-steps of 32 ----
        f32x4 acc[4][4];
        #pragma unroll
        for (int mi = 0; mi < 4; ++mi)
            #pragma unroll
            for (int ni = 0; ni < 4; ++ni) {
                f32x4 z = {0.f, 0.f, 0.f, 0.f};
                acc[mi][ni] = z;
            }

        #pragma unroll
        for (int kk = 0; kk < 4; ++kk) {
            const int ko = kk * 32 + quad * 8;
            bf16x8 af[4], bfv[4];
            #pragma unroll
            for (int mi = 0; mi < 4; ++mi)
                af[mi] = *reinterpret_cast<const bf16x8*>(&a_sm[(wm * 64 + mi * 16 + l16) * LDA + ko]);
            #pragma unroll
            for (int ni = 0; ni < 4; ++ni)
                bfv[ni] = *reinterpret_cast<const bf16x8*>(&b_sm[(wn * 64 + ni * 16 + l16) * LDA + ko]);
            #pragma unroll
            for (int mi = 0; mi < 4; ++mi)
                #pragma unroll
                for (int ni = 0; ni < 4; ++ni)
                    acc[mi][ni] = __builtin_amdgcn_mfma_f32_16x16x32_bf16(af[mi], bfv[ni], acc[mi][ni], 0, 0, 0);
        }

        // ---- epilogue: d^2 = x2 + y2 - 2*xy, clamp >=0, track mins ----
        // C/D layout (verified m89/m91): col j = l16, row i = quad*4 + reg.
        float x2v[16];
        #pragma unroll
        for (int mi = 0; mi < 4; ++mi)
            #pragma unroll
            for (int r = 0; r < 4; ++r)
                x2v[mi * 4 + r] = x2_sm[wm * 64 + mi * 16 + quad * 4 + r];
        float y2v[4];
        #pragma unroll
        for (int ni = 0; ni < 4; ++ni)
            y2v[ni] = y2_sm[wn * 64 + ni * 16 + l16];

        float vcol[4] = {FINF, FINF, FINF, FINF};
        #pragma unroll
        for (int mi = 0; mi < 4; ++mi) {
            #pragma unroll
            for (int r = 0; r < 4; ++r) {
                float vrow = FINF;
                #pragma unroll
                for (int ni = 0; ni < 4; ++ni) {
                    float d2 = fmaxf(x2v[mi * 4 + r] + y2v[ni] - 2.0f * acc[mi][ni][r], 0.0f);
                    vrow = fminf(vrow, d2);
                    vcol[ni] = fminf(vcol[ni], d2);
                }
                // min across the 16 columns held by this quad-row
                vrow = fminf(vrow, __shfl_xor(vrow, 1));
                vrow = fminf(vrow, __shfl_xor(vrow, 2));
                vrow = fminf(vrow, __shfl_xor(vrow, 4));
                vrow = fminf(vrow, __shfl_xor(vrow, 8));
                if (l16 == 0)
                    atomicMin(&row_min_sm[wm * 64 + mi * 16 + quad * 4 + r], __float_as_uint(vrow));
            }
        }
        #pragma unroll
        for (int ni = 0; ni < 4; ++ni) {
            float v = vcol[ni];
            v = fminf(v, __shfl_xor(v, 16));
            v = fminf(v, __shfl_xor(v, 32));
            if (lane < 16)
                atomicMin(&col_min_sm[wn * 64 + ni * 16 + l16], __float_as_uint(v));
        }
        __syncthreads();

        // flush col mins for this j-tile (shared across i-tile blocks -> global atomic)
        if (tid < 128) {
            atomicMin(&g_colmin[n * T + jt * 128 + tid], col_min_sm[tid]);
            col_min_sm[tid] = INF_BITS;
        }
        __syncthreads();
    }

    // row mins are complete within this block (it saw all j)
    if (tid < 128) g_rowmin[n * T + i0 + tid] = row_min_sm[tid];
}

// Phase 2: sum sqrt(min) per direction.
__global__ void wmd_reduce(const unsigned* __restrict__ g_colmin,
                           const unsigned* __restrict__ g_rowmin,
                           float* __restrict__ sums) {
    int n = blockIdx.x, t = threadIdx.x;
    float sc = 0.f, sr = 0.f;
    for (int e = t; e < T; e += 256) {
        sc += sqrtf(__uint_as_float(g_colmin[n * T + e]));
        sr += sqrtf(__uint_as_float(g_rowmin[n * T + e]));
    }
    #pragma unroll
    for (int o = 1; o < 64; o <<= 1) {
        sc += __shfl_xor(sc, o);
        sr += __shfl_xor(sr, o);
    }
    __shared__ float bc[4], br[4];
    int lane = t & 63, wv = t >> 6;
    if (lane == 0) { bc[wv] = sc; br[wv] = sr; }
    __syncthreads();
    if (t == 0) {
        atomicAdd(&sums[0], bc[0] + bc[1] + bc[2] + bc[3]);
        atomicAdd(&sums[1], br[0] + br[1] + br[2] + br[3]);
    }
}

// Phase 3: out = max(fwd, bwd) / scores.size
__global__ void wmd_finalize(const float* __restrict__ sums, float* __restrict__ out) {
    out[0] = fmaxf(sums[0], sums[1]) * (1.0f / 67108864.0f);
}

extern "C" void kernel_launch(void* const* d_in, const int* in_sizes, int n_in,
                              void* d_out, int out_size, void* d_ws, size_t ws_size,
                              hipStream_t stream) {
    const float* x = (const float*)d_in[0];
    const float* y = (const float*)d_in[1];
    float* out = (float*)d_out;

    unsigned* g_colmin = (unsigned*)d_ws;                 // 64*1024 u32
    unsigned* g_rowmin = g_colmin + NB * T;               // 64*1024 u32
    float*    sums     = (float*)(g_rowmin + NB * T);     // 2 floats

    wmd_init<<<(NB * T + 255) / 256, 256, 0, stream>>>(g_colmin, sums);
    wmd_main<<<dim3(T / 128, NB), 256, 0, stream>>>(x, y, g_colmin, g_rowmin);
    wmd_reduce<<<NB, 256, 0, stream>>>(g_colmin, g_rowmin, sums);
    wmd_finalize<<<1, 1, 0, stream>>>(sums, out);
}

// Round 2
// 136.107 us; speedup vs baseline: 1.4402x; 1.4402x over previous
//
#include <hip/hip_runtime.h>

#define NB 64      // L*B batches
#define T 1024     // t1 == t2
#define HD 128     // h

// encoded +inf for order-preserving float-as-uint atomicMin (fenc(+inf))
#define EINF 0xFF800000u

typedef __attribute__((ext_vector_type(8))) short bf16x8;
typedef __attribute__((ext_vector_type(4))) float f32x4;

static __device__ __forceinline__ short f2bf(float f) {
    unsigned u = __float_as_uint(f);
    u += 0x7FFFu + ((u >> 16) & 1u);
    return (short)(u >> 16);
}

// order-preserving float -> uint (works for negatives), and inverse
static __device__ __forceinline__ unsigned fenc(float f) {
    unsigned b = __float_as_uint(f);
    return b ^ (unsigned)(((int)b >> 31) | (int)0x80000000);
}
static __device__ __forceinline__ float fdec(unsigned u) {
    unsigned m = (~(unsigned)((int)u >> 31)) | 0x80000000u;
    return __uint_as_float(u ^ m);
}

// Phase 0: init col-min workspace to encoded +inf, zero sums.
__global__ void wmd_init(unsigned* __restrict__ g_colmin, float* __restrict__ sums) {
    int t = blockIdx.x * 256 + threadIdx.x;
    if (t < NB * T) g_colmin[t] = EINF;
    if (t < 2) sums[t] = 0.f;
}

// Phase 0b: y fp32 -> bf16 (row-major) + per-row squared norms. Memory-bound.
__global__ void wmd_convy(const float* __restrict__ y, short* __restrict__ ybf,
                          float* __restrict__ y2) {
    int idx = blockIdx.x * 256 + threadIdx.x;   // float4 index; 32 per row
    float4 v = reinterpret_cast<const float4*>(y)[idx];
    short4 s4;
    s4.x = f2bf(v.x); s4.y = f2bf(v.y); s4.z = f2bf(v.z); s4.w = f2bf(v.w);
    reinterpret_cast<short4*>(ybf)[idx] = s4;
    float p = v.x * v.x + v.y * v.y + v.z * v.z + v.w * v.w;
    p += __shfl_xor(p, 1);  p += __shfl_xor(p, 2);  p += __shfl_xor(p, 4);
    p += __shfl_xor(p, 8);  p += __shfl_xor(p, 16);
    if ((threadIdx.x & 31) == 0) y2[idx >> 5] = p;
}

// Phase 1: fused bf16-MFMA GEMM + min tracking.
// Grid: (8 i-tiles, 64 batches). Block: 256 threads = 2x2 waves of 64x64.
// B staged via global_load_lds (16B) into XOR-swizzled LDS, double-buffered.
// A converted in-kernel once, fragments resident in registers (K=128).
__global__ __launch_bounds__(256, 2)
void wmd_main(const float* __restrict__ x, const short* __restrict__ ybf,
              const float* __restrict__ y2, unsigned* __restrict__ g_colmin,
              float* __restrict__ g_rowmin) {
    __shared__ short b_sm[2][128 * 128];        // 2 x 32 KB, swizzled chunks
    __shared__ float x2_sm[128];
    __shared__ unsigned col_min_sm[1024];       // encoded partial col mins (all j)
    __shared__ unsigned row_min_sm[128];

    const int tid  = threadIdx.x;
    const int n    = blockIdx.y;
    const int i0   = blockIdx.x * 128;
    const int lane = tid & 63;
    const int wave = tid >> 6;
    const int wm   = wave >> 1, wn = wave & 1;
    const int l16  = lane & 15, quad = lane >> 4;
    const float FINF = __uint_as_float(0x7F800000u);

    #pragma unroll
    for (int e = tid; e < 1024; e += 256) col_min_sm[e] = EINF;
    if (tid < 128) row_min_sm[tid] = EINF;

    // ---- stage A tile (fp32 -> bf16) into swizzled b_sm[0] + exact row norms ----
    {
        const float4* xg = reinterpret_cast<const float4*>(x + (size_t)(n * T + i0) * HD);
        #pragma unroll
        for (int it = 0; it < 16; ++it) {
            int idx = it * 256 + tid;
            int row = idx >> 5, c4 = idx & 31;       // 32 float4 per 128-row
            float4 v = xg[idx];
            short4 s4;
            s4.x = f2bf(v.x); s4.y = f2bf(v.y); s4.z = f2bf(v.z); s4.w = f2bf(v.w);
            int c  = c4 >> 1;                        // 16B chunk column 0..15
            int sw = c ^ (row & 7);                  // swizzled chunk
            *reinterpret_cast<short4*>(&b_sm[0][(row * 16 + sw) * 8 + (c4 & 1) * 4]) = s4;
            float p = v.x * v.x + v.y * v.y + v.z * v.z + v.w * v.w;
            p += __shfl_xor(p, 1);  p += __shfl_xor(p, 2);  p += __shfl_xor(p, 4);
            p += __shfl_xor(p, 8);  p += __shfl_xor(p, 16);
            if ((tid & 31) == 0) x2_sm[row] = p;
        }
    }
    __syncthreads();

    // ---- A fragments to registers (full K=128 resident) + x2 ----
    bf16x8 af[4][4];
    #pragma unroll
    for (int mi = 0; mi < 4; ++mi)
        #pragma unroll
        for (int kk = 0; kk < 4; ++kk) {
            int row = wm * 64 + mi * 16 + l16;
            int c   = kk * 4 + quad;
            af[mi][kk] = *reinterpret_cast<const bf16x8*>(
                &b_sm[0][(row * 16 + (c ^ (row & 7))) * 8]);
        }
    float x2v[16];
    #pragma unroll
    for (int mi = 0; mi < 4; ++mi)
        #pragma unroll
        for (int r = 0; r < 4; ++r)
            x2v[mi * 4 + r] = x2_sm[wm * 64 + mi * 16 + quad * 4 + r];
    float rmin[16];
    #pragma unroll
    for (int q = 0; q < 16; ++q) rmin[q] = FINF;

    // async stage of B tile jt into buffer p (XOR-swizzled via source permutation)
#define ISSUE_GLLS(pbuf, jtile)                                                   \
    {                                                                             \
        const short* ybase = ybf + (((size_t)(n * T + (jtile) * 128)) << 7);      \
        _Pragma("unroll")                                                         \
        for (int it = 0; it < 8; ++it) {                                          \
            int g   = wave * 8 + it;                                              \
            int s   = g * 64 + lane;                                              \
            int row = s >> 4;                                                     \
            int c   = (s & 15) ^ (row & 7);                                       \
            const short* gp = ybase + row * 128 + c * 8;                          \
            __builtin_amdgcn_global_load_lds(                                     \
                (const __attribute__((address_space(1))) void*)gp,                \
                (__attribute__((address_space(3))) void*)&b_sm[pbuf][g * 512],    \
                16, 0, 0);                                                        \
        }                                                                         \
    }

    ISSUE_GLLS(1, 0);

    for (int jt = 0; jt < 8; ++jt) {
        const int p = (jt & 1) ^ 1;              // buffer holding tile jt
        __syncthreads();                         // drains DMA for tile jt
        if (jt < 7) ISSUE_GLLS(p ^ 1, jt + 1);   // overlap next tile with compute

        float y2v[4];
        #pragma unroll
        for (int ni = 0; ni < 4; ++ni)
            y2v[ni] = y2[n * T + jt * 128 + wn * 64 + ni * 16 + l16];

        f32x4 acc[4][4];
        #pragma unroll
        for (int mi = 0; mi < 4; ++mi)
            #pragma unroll
            for (int ni = 0; ni < 4; ++ni) {
                f32x4 z = {0.f, 0.f, 0.f, 0.f};
                acc[mi][ni] = z;
            }

        #pragma unroll
        for (int kk = 0; kk < 4; ++kk) {
            bf16x8 bv[4];
            #pragma unroll
            for (int ni = 0; ni < 4; ++ni) {
                int row = wn * 64 + ni * 16 + l16;
                int c   = kk * 4 + quad;
                bv[ni] = *reinterpret_cast<const bf16x8*>(
                    &b_sm[p][(row * 16 + (c ^ (row & 7))) * 8]);
            }
            #pragma unroll
            for (int mi = 0; mi < 4; ++mi)
                #pragma unroll
                for (int ni = 0; ni < 4; ++ni)
                    acc[mi][ni] = __builtin_amdgcn_mfma_f32_16x16x32_bf16(
                        af[mi][kk], bv[ni], acc[mi][ni], 0, 0, 0);
        }

        // ---- epilogue: fold mins (clamp + norm-add deferred; 2 fma + 2 fmin / score)
        float vcol[4] = {FINF, FINF, FINF, FINF};
        #pragma unroll
        for (int mi = 0; mi < 4; ++mi)
            #pragma unroll
            for (int r = 0; r < 4; ++r) {
                float x2r = x2v[mi * 4 + r];
                #pragma unroll
                for (int ni = 0; ni < 4; ++ni) {
                    float xy = acc[mi][ni][r];
                    rmin[mi * 4 + r] = fminf(rmin[mi * 4 + r], fmaf(-2.f, xy, y2v[ni]));
                    vcol[ni]         = fminf(vcol[ni],         fmaf(-2.f, xy, x2r));
                }
            }
        #pragma unroll
        for (int ni = 0; ni < 4; ++ni) {
            float v = vcol[ni];
            v = fminf(v, __shfl_xor(v, 16));
            v = fminf(v, __shfl_xor(v, 32));
            if (lane < 16)
                atomicMin(&col_min_sm[jt * 128 + wn * 64 + ni * 16 + lane], fenc(v));
        }
    }

    // ---- final flush ----
    #pragma unroll
    for (int mi = 0; mi < 4; ++mi)
        #pragma unroll
        for (int r = 0; r < 4; ++r) {
            float v = rmin[mi * 4 + r];
            v = fminf(v, __shfl_xor(v, 1));
            v = fminf(v, __shfl_xor(v, 2));
            v = fminf(v, __shfl_xor(v, 4));
            v = fminf(v, __shfl_xor(v, 8));
            if (l16 == 0)
                atomicMin(&row_min_sm[wm * 64 + mi * 16 + quad * 4 + r], fenc(v));
        }
    __syncthreads();
    if (tid < 128) {
        float rv = fdec(row_min_sm[tid]) + x2_sm[tid];
        g_rowmin[n * T + i0 + tid] = fmaxf(rv, 0.f);   // clamped d^2
    }
    #pragma unroll
    for (int e = tid; e < 1024; e += 256)
        atomicMin(&g_colmin[n * T + e], col_min_sm[e]);
}

// Phase 2: sum sqrt(min d^2) per direction.
__global__ void wmd_reduce(const unsigned* __restrict__ g_colmin,
                           const float* __restrict__ g_rowmin,
                           const float* __restrict__ y2,
                           float* __restrict__ sums) {
    int n = blockIdx.x, t = threadIdx.x;
    float sc = 0.f, sr = 0.f;
    for (int e = t; e < T; e += 256) {
        float cv = fdec(g_colmin[n * T + e]) + y2[n * T + e];
        sc += sqrtf(fmaxf(cv, 0.f));
        sr += sqrtf(g_rowmin[n * T + e]);
    }
    #pragma unroll
    for (int o = 1; o < 64; o <<= 1) {
        sc += __shfl_xor(sc, o);
        sr += __shfl_xor(sr, o);
    }
    __shared__ float bc[4], br[4];
    int lane = t & 63, wv = t >> 6;
    if (lane == 0) { bc[wv] = sc; br[wv] = sr; }
    __syncthreads();
    if (t == 0) {
        atomicAdd(&sums[0], bc[0] + bc[1] + bc[2] + bc[3]);
        atomicAdd(&sums[1], br[0] + br[1] + br[2] + br[3]);
    }
}

// Phase 3: out = max(fwd, bwd) / scores.size
__global__ void wmd_finalize(const float* __restrict__ sums, float* __restrict__ out) {
    out[0] = fmaxf(sums[0], sums[1]) * (1.0f / 67108864.0f);
}

extern "C" void kernel_launch(void* const* d_in, const int* in_sizes, int n_in,
                              void* d_out, int out_size, void* d_ws, size_t ws_size,
                              hipStream_t stream) {
    const float* x = (const float*)d_in[0];
    const float* y = (const float*)d_in[1];
    float* out = (float*)d_out;

    char* ws = (char*)d_ws;
    unsigned* g_colmin = (unsigned*)(ws);                    // 64K u32  = 256 KB
    float*    g_rowmin = (float*)(ws + 256 * 1024);          // 64K f32  = 256 KB
    float*    y2       = (float*)(ws + 512 * 1024);          // 64K f32  = 256 KB
    float*    sums     = (float*)(ws + 768 * 1024);          // 2 f32
    short*    ybf      = (short*)(ws + 1024 * 1024);         // 8.4M shorts = 16.8 MB... (64*1024*128)*2B = 16 MB

    wmd_init<<<(NB * T + 255) / 256, 256, 0, stream>>>(g_colmin, sums);
    wmd_convy<<<(NB * T * HD / 4) / 256, 256, 0, stream>>>(y, ybf, y2);
    wmd_main<<<dim3(T / 128, NB), 256, 0, stream>>>(x, ybf, y2, g_colmin, g_rowmin);
    wmd_reduce<<<NB, 256, 0, stream>>>(g_colmin, g_rowmin, y2, sums);
    wmd_finalize<<<1, 1, 0, stream>>>(sums, out);
}

// Round 3
// 127.430 us; speedup vs baseline: 1.5382x; 1.0681x over previous
//
#include <hip/hip_runtime.h>

#define NB 64      // L*B batches
#define T 1024     // t1 == t2
#define HD 128     // h

// encoded +inf for order-preserving float-as-uint atomicMin
#define EINF 0xFF800000u

typedef __attribute__((ext_vector_type(8))) short bf16x8;
typedef __attribute__((ext_vector_type(4))) float f32x4;

static __device__ __forceinline__ short f2bf(float f) {
    unsigned u = __float_as_uint(f);
    u += 0x7FFFu + ((u >> 16) & 1u);
    return (short)(u >> 16);
}
static __device__ __forceinline__ unsigned fenc(float f) {
    unsigned b = __float_as_uint(f);
    return b ^ (unsigned)(((int)b >> 31) | (int)0x80000000);
}
static __device__ __forceinline__ float fdec(unsigned u) {
    unsigned m = (~(unsigned)((int)u >> 31)) | 0x80000000u;
    return __uint_as_float(u ^ m);
}

// Phase 0: y fp32 -> bf16 + per-row norms, plus all workspace init (one kernel).
__global__ void wmd_prep(const float* __restrict__ y, short* __restrict__ ybf,
                         float* __restrict__ y2, unsigned* __restrict__ g_colmin,
                         unsigned* __restrict__ g_rowmin, float* __restrict__ sums,
                         unsigned* __restrict__ counter) {
    int gi = blockIdx.x * 256 + threadIdx.x;          // float4 index, 2M total
    float4 v = reinterpret_cast<const float4*>(y)[gi];
    short4 s4;
    s4.x = f2bf(v.x); s4.y = f2bf(v.y); s4.z = f2bf(v.z); s4.w = f2bf(v.w);
    reinterpret_cast<short4*>(ybf)[gi] = s4;
    float p = v.x * v.x + v.y * v.y + v.z * v.z + v.w * v.w;
    p += __shfl_xor(p, 1);  p += __shfl_xor(p, 2);  p += __shfl_xor(p, 4);
    p += __shfl_xor(p, 8);  p += __shfl_xor(p, 16);
    if ((threadIdx.x & 31) == 0) y2[gi >> 5] = p;
    if (gi < NB * T) { g_colmin[gi] = EINF; g_rowmin[gi] = EINF; }
    if (gi < 2) sums[gi] = 0.f;
    if (gi == 2) counter[0] = 0u;
}

// Phase 1: fused bf16-MFMA GEMM + min tracking.
// Grid: (8 i-tiles x 2 j-halves, 64 batches) = 1024 blocks, 256 threads.
// Per wave: 32i x 64j tile. B: 64x128 tiles DMA'd (global_load_lds 16B,
// XOR-swizzled), double-buffered. A fragments loaded fp32->bf16 direct to regs.
__global__ __launch_bounds__(256, 4)
void wmd_main(const float* __restrict__ x, const short* __restrict__ ybf,
              const float* __restrict__ y2g, unsigned* __restrict__ g_colmin,
              unsigned* __restrict__ g_rowmin, float* __restrict__ x2g) {
    __shared__ short b_sm[2][64 * 128];        // 2 x 16 KB
    __shared__ float y2_sm[512];
    __shared__ float x2_sm[128];
    __shared__ unsigned col_min_sm[512];

    const int tid  = threadIdx.x;
    const int n    = blockIdx.y;
    const int bx   = blockIdx.x;
    const int i0   = (bx & 7) * 128;
    const int j0   = (bx >> 3) * 512;
    const int lane = tid & 63;
    const int wave = tid >> 6;
    const int l16  = lane & 15, quad = lane >> 4;
    const float FINF = __uint_as_float(0x7F800000u);

    #pragma unroll
    for (int e = tid; e < 512; e += 256) col_min_sm[e] = EINF;

#define ISSUE_GLLS(pbuf, jtile)                                                   \
    {                                                                             \
        const short* ybase = ybf + (((size_t)(n * T + j0 + (jtile) * 64)) << 7);  \
        _Pragma("unroll")                                                         \
        for (int it = 0; it < 4; ++it) {                                          \
            int g   = wave * 4 + it;                                              \
            int s   = g * 64 + lane;                                              \
            int row = s >> 4;                                                     \
            int c   = (s & 15) ^ (row & 7);                                       \
            const short* gp = ybase + row * 128 + c * 8;                          \
            __builtin_amdgcn_global_load_lds(                                     \
                (const __attribute__((address_space(1))) void*)gp,                \
                (__attribute__((address_space(3))) void*)&b_sm[pbuf][g * 512],    \
                16, 0, 0);                                                        \
        }                                                                         \
    }

    ISSUE_GLLS(0, 0);   // overlap tile-0 DMA with A staging

    // ---- A fragments: global fp32 -> bf16 regs; exact row norms via shuffles ----
    bf16x8 af[2][4];
    #pragma unroll
    for (int mi = 0; mi < 2; ++mi) {
        float part = 0.f;
        #pragma unroll
        for (int kk = 0; kk < 4; ++kk) {
            const float4* gp = reinterpret_cast<const float4*>(
                x + (((size_t)(n * T + i0 + wave * 32 + mi * 16 + l16)) << 7) + kk * 32 + quad * 8);
            float4 a = gp[0], b = gp[1];
            bf16x8 f;
            f[0] = f2bf(a.x); f[1] = f2bf(a.y); f[2] = f2bf(a.z); f[3] = f2bf(a.w);
            f[4] = f2bf(b.x); f[5] = f2bf(b.y); f[6] = f2bf(b.z); f[7] = f2bf(b.w);
            af[mi][kk] = f;
            part += a.x * a.x + a.y * a.y + a.z * a.z + a.w * a.w;
            part += b.x * b.x + b.y * b.y + b.z * b.z + b.w * b.w;
        }
        part += __shfl_xor(part, 16);
        part += __shfl_xor(part, 32);
        if (quad == 0) {
            x2_sm[wave * 32 + mi * 16 + l16] = part;
            x2g[n * T + i0 + wave * 32 + mi * 16 + l16] = part;  // dup write ok
        }
    }
    // ---- y2 for this block's j-half into LDS ----
    #pragma unroll
    for (int e = tid; e < 512; e += 256) y2_sm[e] = y2g[n * T + j0 + e];

    float rmin[8];
    #pragma unroll
    for (int q = 0; q < 8; ++q) rmin[q] = FINF;

    __syncthreads();    // x2_sm/y2_sm visible; tile-0 DMA drained

    float x2v[8];
    #pragma unroll
    for (int mi = 0; mi < 2; ++mi)
        #pragma unroll
        for (int r = 0; r < 4; ++r)
            x2v[mi * 4 + r] = x2_sm[wave * 32 + mi * 16 + quad * 4 + r];

    for (int jt = 0; jt < 8; ++jt) {
        const int p = jt & 1;
        if (jt < 7) ISSUE_GLLS(p ^ 1, jt + 1);   // overlaps this iter's compute

        float y2v[4];
        #pragma unroll
        for (int ni = 0; ni < 4; ++ni)
            y2v[ni] = y2_sm[jt * 64 + ni * 16 + l16];

        f32x4 acc[2][4];
        #pragma unroll
        for (int mi = 0; mi < 2; ++mi)
            #pragma unroll
            for (int ni = 0; ni < 4; ++ni) {
                f32x4 z = {0.f, 0.f, 0.f, 0.f};
                acc[mi][ni] = z;
            }

        #pragma unroll
        for (int kk = 0; kk < 4; ++kk) {
            bf16x8 bv[4];
            #pragma unroll
            for (int ni = 0; ni < 4; ++ni) {
                int row = ni * 16 + l16;
                int c   = (kk * 4 + quad) ^ (row & 7);
                bv[ni] = *reinterpret_cast<const bf16x8*>(&b_sm[p][(row * 16 + c) * 8]);
            }
            #pragma unroll
            for (int mi = 0; mi < 2; ++mi)
                #pragma unroll
                for (int ni = 0; ni < 4; ++ni)
                    acc[mi][ni] = __builtin_amdgcn_mfma_f32_16x16x32_bf16(
                        af[mi][kk], bv[ni], acc[mi][ni], 0, 0, 0);
        }

        // ---- epilogue: fold mins (norm-add + clamp deferred) ----
        float vcol[4] = {FINF, FINF, FINF, FINF};
        #pragma unroll
        for (int mi = 0; mi < 2; ++mi)
            #pragma unroll
            for (int r = 0; r < 4; ++r) {
                float x2r = x2v[mi * 4 + r];
                #pragma unroll
                for (int ni = 0; ni < 4; ++ni) {
                    float xy = acc[mi][ni][r];
                    rmin[mi * 4 + r] = fminf(rmin[mi * 4 + r], fmaf(-2.f, xy, y2v[ni]));
                    vcol[ni]         = fminf(vcol[ni],         fmaf(-2.f, xy, x2r));
                }
            }
        #pragma unroll
        for (int ni = 0; ni < 4; ++ni) {
            float v = vcol[ni];
            v = fminf(v, __shfl_xor(v, 16));
            v = fminf(v, __shfl_xor(v, 32));
            if (lane < 16)
                atomicMin(&col_min_sm[jt * 64 + ni * 16 + lane], fenc(v));
        }
        __syncthreads();   // drains next-tile DMA; orders buffer reuse + LDS atomics
    }

    // ---- flush: rows are unique per lane -> direct global atomicMin ----
    #pragma unroll
    for (int mi = 0; mi < 2; ++mi)
        #pragma unroll
        for (int r = 0; r < 4; ++r) {
            float v = rmin[mi * 4 + r];
            v = fminf(v, __shfl_xor(v, 1));
            v = fminf(v, __shfl_xor(v, 2));
            v = fminf(v, __shfl_xor(v, 4));
            v = fminf(v, __shfl_xor(v, 8));
            if (l16 == 0)
                atomicMin(&g_rowmin[n * T + i0 + wave * 32 + mi * 16 + quad * 4 + r], fenc(v));
        }
    #pragma unroll
    for (int e = tid; e < 512; e += 256)
        atomicMin(&g_colmin[n * T + j0 + e], col_min_sm[e]);
}

// Phase 2: sum sqrt(min d^2) per direction; last block finalizes (counter trick).
__global__ void wmd_reduce(const unsigned* __restrict__ g_colmin,
                           const unsigned* __restrict__ g_rowmin,
                           const float* __restrict__ x2g,
                           const float* __restrict__ y2g,
                           float* __restrict__ sums,
                           unsigned* __restrict__ counter,
                           float* __restrict__ out) {
    int n = blockIdx.x, t = threadIdx.x;
    float sc = 0.f, sr = 0.f;
    for (int e = t; e < T; e += 256) {
        float cv = fdec(g_colmin[n * T + e]) + y2g[n * T + e];
        float rv = fdec(g_rowmin[n * T + e]) + x2g[n * T + e];
        sc += sqrtf(fmaxf(cv, 0.f));
        sr += sqrtf(fmaxf(rv, 0.f));
    }
    #pragma unroll
    for (int o = 1; o < 64; o <<= 1) {
        sc += __shfl_xor(sc, o);
        sr += __shfl_xor(sr, o);
    }
    __shared__ float bc[4], br[4];
    int lane = t & 63, wv = t >> 6;
    if (lane == 0) { bc[wv] = sc; br[wv] = sr; }
    __syncthreads();
    if (t == 0) {
        atomicAdd(&sums[0], bc[0] + bc[1] + bc[2] + bc[3]);
        atomicAdd(&sums[1], br[0] + br[1] + br[2] + br[3]);
        __threadfence();
        unsigned old = atomicAdd(counter, 1u);
        if (old == NB - 1) {
            float a = atomicAdd(&sums[0], 0.f);   // coherent reads
            float b = atomicAdd(&sums[1], 0.f);
            out[0] = fmaxf(a, b) * (1.0f / 67108864.0f);
        }
    }
}

extern "C" void kernel_launch(void* const* d_in, const int* in_sizes, int n_in,
                              void* d_out, int out_size, void* d_ws, size_t ws_size,
                              hipStream_t stream) {
    const float* x = (const float*)d_in[0];
    const float* y = (const float*)d_in[1];
    float* out = (float*)d_out;

    char* ws = (char*)d_ws;
    unsigned* g_colmin = (unsigned*)(ws);                    // 256 KB
    unsigned* g_rowmin = (unsigned*)(ws + 256 * 1024);       // 256 KB
    float*    x2g      = (float*)(ws + 512 * 1024);          // 256 KB
    float*    y2g      = (float*)(ws + 768 * 1024);          // 256 KB
    float*    sums     = (float*)(ws + 1024 * 1024);         // 2 f32
    unsigned* counter  = (unsigned*)(ws + 1024 * 1024 + 8);  // 1 u32
    short*    ybf      = (short*)(ws + 1024 * 1024 + 4096);  // 16 MB

    wmd_prep<<<(NB * T * HD / 4) / 256, 256, 0, stream>>>(y, ybf, y2g, g_colmin,
                                                          g_rowmin, sums, counter);
    wmd_main<<<dim3(16, NB), 256, 0, stream>>>(x, ybf, y2g, g_colmin, g_rowmin, x2g);
    wmd_reduce<<<NB, 256, 0, stream>>>(g_colmin, g_rowmin, x2g, y2g, sums, counter, out);
}